// Round 4
// baseline (19616.951 us; speedup 1.0000x reference)
//
#include <hip/hip_runtime.h>

#define TT    1024   // timesteps
#define BATCH 2048
#define NI    6      // input dim
#define NH    38     // hidden
#define NHP   40     // padded hidden row (10 x float4; pads stay 0)
#define NCLS  8      // classes
#define NB    8      // batches per block
#define BLK   1024   // 16 waves: 0-4 L1, 5-9 L2q, 10-14 L2p, 15 x-prefetch
#define GRID  (BATCH / NB)   // 256 blocks = 1 block/CU, single dispatch round

__device__ __forceinline__ float fsig(float v) {
    return __fdividef(1.0f, 1.0f + __expf(-v));
}

// quad-broadcast lane (base+g) of each aligned 4-lane group (literal patterns)
#define QB0 0x8000
#define QB1 0x8055
#define QB2 0x80AA
#define QB3 0x80FF
#define QBCAST(v, pat) __int_as_float(__builtin_amdgcn_ds_swizzle(__float_as_int(v), pat))

// NOTE: no second __launch_bounds__ arg! Rounds 2/3 proved this toolchain
// treats it as min-BLOCKS/CU: (448,4)->64 VGPR, (1024,4)->64 VGPR -> scratch
// spill -> 51 GB HBM traffic/dispatch. With max-threads=1024 alone the
// backend caps at 128 VGPR (4 waves/SIMD), which fits our ~90 live floats.
__global__ __launch_bounds__(BLK) void lstm2_kernel(
    const float* __restrict__ x,
    const float* __restrict__ Wih0, const float* __restrict__ Whh0, const float* __restrict__ b0,
    const float* __restrict__ Wih1, const float* __restrict__ Whh1, const float* __restrict__ b1,
    const float* __restrict__ Wc,   const float* __restrict__ bc,
    float* __restrict__ out)
{
    __shared__ __align__(16) float h1buf[2][NB][NHP];
    __shared__ __align__(16) float h2buf[2][NB][NHP];
    __shared__ __align__(16) float qbuf[NB][4][NHP];  // [batch][gate][unit] pad->2-way
    __shared__ float xbuf[4][NB][NI];                 // 4-slot x staging, t+2 ahead

    const int tid   = threadIdx.x;
    const int wv    = tid >> 6;
    const int bbase = blockIdx.x * NB;

    // zero both h slots (pads included -> pads stay 0 forever; w pads are 0 too)
    for (int idx = tid; idx < 2 * NB * NHP; idx += BLK) {
        (&h1buf[0][0][0])[idx] = 0.0f;
        (&h2buf[0][0][0])[idx] = 0.0f;
    }
    // preload x(0), x(1)
    if (tid < 2 * NB * NI) {
        const int slot = tid / (NB * NI), r2 = tid % (NB * NI);
        const int b = r2 / NI, i = r2 % NI;
        xbuf[slot][b][i] = x[((size_t)(bbase + b) * TT + slot) * NI + i];
    }

    // roles: 0=L1 (full layer-1 cell), 1=L2q (Whh1 partial), 2=L2p (combine+cell), 3=x prefetch
    int role, l;
    if      (wv < 5)  { role = 0; l = tid; }
    else if (wv < 10) { role = 1; l = tid - 320; }
    else if (wv < 15) { role = 2; l = tid - 640; }
    else              { role = 3; l = tid - 960; }

    // thread = (gate row, 4-batch half); 152 rows x 2 halves = 304 of 320 lanes
    bool act = false;
    int bh = 0, u = 0, g = 0;
    if (role <= 2) {
        act = (l < 304);
        const int la = act ? l : 0;
        bh = (la >= 152) ? 1 : 0;
        const int r = la - bh * 152;
        u = r >> 2;            // unit 0..37
        g = r & 3;             // gate: quads stay aligned (152 % 4 == 0)
    }
    const int grow = g * NH + u;   // gate-row index in 4H-major weight layout

    // register-resident weights: exactly ONE row per thread (~47 floats) -> no spill
    float w[NHP];                 // L1: Whh0 row; L2q: Whh1 row; L2p: Wih1 row
    float wx[NI] = {0,0,0,0,0,0}; // L1 only: Wih0 row
    float bias = 0.0f;
    float cst[4] = {0.f, 0.f, 0.f, 0.f};

    if (role <= 2) {
        const float* rw = (role == 0) ? (Whh0 + (size_t)grow * NH)
                        : (role == 1) ? (Whh1 + (size_t)grow * NH)
                        :               (Wih1 + (size_t)grow * NH);
        #pragma unroll
        for (int k = 0; k < NH; ++k) w[k] = rw[k];
        w[38] = 0.f; w[39] = 0.f;
        if (role == 0) {
            const float* rx = Wih0 + (size_t)grow * NI;
            #pragma unroll
            for (int i = 0; i < NI; ++i) wx[i] = rx[i];
            bias = b0[grow];
        } else if (role == 2) {
            bias = b1[grow];
        }
    }

    // own-gate activation: gate 2 is tanh(a) = 2*sigmoid(2a) - 1
    const float k1 = (g == 2) ? 2.0f : 1.0f;
    const float k2 = (g == 2) ? 2.0f : 1.0f;
    const float k3 = (g == 2) ? -1.0f : 0.0f;

    __syncthreads();

    #pragma unroll 1
    for (int t = 0; t < TT; ++t) {
        const int cur = t & 1, prv = cur ^ 1, xs = t & 3;

        // ---------------- phase 1 ----------------
        if (role == 0) {
            // layer 1: a = b0 + Wih0 x(t) + Whh0 h1(t-1); pointwise via quad swizzle
            float acc[4];
            #pragma unroll
            for (int ib = 0; ib < 4; ++ib) {
                acc[ib] = bias;
                const int b = bh * 4 + ib;
                #pragma unroll
                for (int i = 0; i < NI; ++i) acc[ib] += wx[i] * xbuf[xs][b][i];
            }
            const float4* h4 = (const float4*)(&h1buf[prv][bh * 4][0]);
            #pragma unroll
            for (int c4 = 0; c4 < 10; ++c4) {
                #pragma unroll
                for (int ib = 0; ib < 4; ++ib) {   // 4 independent FMA chains
                    const float4 hv = h4[ib * 10 + c4];
                    acc[ib] += w[4*c4+0] * hv.x; acc[ib] += w[4*c4+1] * hv.y;
                    acc[ib] += w[4*c4+2] * hv.z; acc[ib] += w[4*c4+3] * hv.w;
                }
            }
            #pragma unroll
            for (int ib = 0; ib < 4; ++ib) {
                const int b = bh * 4 + ib;
                const float v  = fsig(acc[ib] * k1) * k2 + k3;
                const float gi = QBCAST(v, QB0);
                const float gf = QBCAST(v, QB1);
                const float gg = QBCAST(v, QB2);
                const float go = QBCAST(v, QB3);
                const float c  = gf * cst[ib] + gi * gg;
                cst[ib] = c;
                const float h = go * (2.0f * fsig(2.0f * c) - 1.0f);
                if (act && g == 0) h1buf[cur][b][u] = h;
            }
        } else if (role == 1) {
            // layer-2 recurrent partial: q = Whh1 h2(t-1)  (independent of h1(t))
            float acc[4] = {0.f, 0.f, 0.f, 0.f};
            const float4* h4 = (const float4*)(&h2buf[prv][bh * 4][0]);
            #pragma unroll
            for (int c4 = 0; c4 < 10; ++c4) {
                #pragma unroll
                for (int ib = 0; ib < 4; ++ib) {
                    const float4 hv = h4[ib * 10 + c4];
                    acc[ib] += w[4*c4+0] * hv.x; acc[ib] += w[4*c4+1] * hv.y;
                    acc[ib] += w[4*c4+2] * hv.z; acc[ib] += w[4*c4+3] * hv.w;
                }
            }
            if (act) {
                #pragma unroll
                for (int ib = 0; ib < 4; ++ib) qbuf[bh * 4 + ib][g][u] = acc[ib];
            }
        } else if (role == 3) {
            // x prefetch, 2 steps ahead (HBM latency hidden across 2 steps)
            if (l < NB * NI && t + 2 < TT) {
                const int b = l / NI, i = l % NI;
                xbuf[(t + 2) & 3][b][i] = x[((size_t)(bbase + b) * TT + (t + 2)) * NI + i];
            }
        }
        __syncthreads();

        // ---------------- phase 2 ----------------
        if (role == 2) {
            // layer 2: a = b1 + q + Wih1 h1(t); pointwise via quad swizzle
            float acc[4];
            #pragma unroll
            for (int ib = 0; ib < 4; ++ib) acc[ib] = bias + qbuf[bh * 4 + ib][g][u];
            const float4* h4 = (const float4*)(&h1buf[cur][bh * 4][0]);
            #pragma unroll
            for (int c4 = 0; c4 < 10; ++c4) {
                #pragma unroll
                for (int ib = 0; ib < 4; ++ib) {
                    const float4 hv = h4[ib * 10 + c4];
                    acc[ib] += w[4*c4+0] * hv.x; acc[ib] += w[4*c4+1] * hv.y;
                    acc[ib] += w[4*c4+2] * hv.z; acc[ib] += w[4*c4+3] * hv.w;
                }
            }
            #pragma unroll
            for (int ib = 0; ib < 4; ++ib) {
                const int b = bh * 4 + ib;
                const float v  = fsig(acc[ib] * k1) * k2 + k3;
                const float gi = QBCAST(v, QB0);
                const float gf = QBCAST(v, QB1);
                const float gg = QBCAST(v, QB2);
                const float go = QBCAST(v, QB3);
                const float c  = gf * cst[ib] + gi * gg;
                cst[ib] = c;
                const float h = go * (2.0f * fsig(2.0f * c) - 1.0f);
                if (act && g == 0) h2buf[cur][b][u] = h;
            }
        }
        __syncthreads();
    }

    // epilogue: out = h2(T-1) @ Wc.T + bc ; TT-1 odd -> slot 1
    if (tid < NB * NCLS) {
        const int b = tid / NCLS, c = tid % NCLS;
        float acc = bc[c];
        #pragma unroll
        for (int k = 0; k < NH; ++k) acc += Wc[c * NH + k] * h2buf[1][b][k];
        out[(size_t)(bbase + b) * NCLS + c] = acc;
    }
}

extern "C" void kernel_launch(void* const* d_in, const int* in_sizes, int n_in,
                              void* d_out, int out_size, void* d_ws, size_t ws_size,
                              hipStream_t stream) {
    const float* x    = (const float*)d_in[0];
    const float* Wih0 = (const float*)d_in[1];
    const float* Whh0 = (const float*)d_in[2];
    const float* b0   = (const float*)d_in[3];
    const float* Wih1 = (const float*)d_in[4];
    const float* Whh1 = (const float*)d_in[5];
    const float* b1   = (const float*)d_in[6];
    const float* Wc   = (const float*)d_in[7];
    const float* bc   = (const float*)d_in[8];
    float* out = (float*)d_out;

    hipLaunchKernelGGL(lstm2_kernel, dim3(GRID), dim3(BLK), 0, stream,
                       x, Wih0, Whh0, b0, Wih1, Whh1, b1, Wc, bc, out);
}

// Round 5
// 6236.032 us; speedup vs baseline: 3.1457x; 3.1457x over previous
//
#include <hip/hip_runtime.h>

#define TT    1024   // timesteps
#define BATCH 2048
#define NI    6      // input dim
#define NH    38     // hidden
#define NHP   40     // padded hidden row (10 x float4; pads stay 0)
#define NCLS  8      // classes
#define NB    4      // batches per block
#define BLK   512    // 8 waves; roles in 160-thread groups (quad-aligned)
#define GRID  (BATCH / NB)   // 512 blocks = 2 blocks/CU

__device__ __forceinline__ float fsig(float v) {
    return __fdividef(1.0f, 1.0f + __expf(-v));
}

// quad-broadcast lane (base+g) of each aligned 4-lane group (literal patterns)
#define QB0 0x8000
#define QB1 0x8055
#define QB2 0x80AA
#define QB3 0x80FF
#define QBCAST(v, pat) __int_as_float(__builtin_amdgcn_ds_swizzle(__float_as_int(v), pat))

// REGISTER REGIME (hard-won across rounds 1-4):
//   BLK=1024 (16 waves) forces >=4 waves/SIMD -> <=128 regs -> allocator
//   chose 64 -> scratch spill -> 51 GB HBM/dispatch (rounds 3,4).
//   BLK=512 + __launch_bounds__(512,2) is the ONLY config observed to stay
//   fully on-chip (round 1: VGPR=112, WRITE_SIZE=64 KB). Keep it.
__global__ __launch_bounds__(BLK, 2) void lstm2_kernel(
    const float* __restrict__ x,
    const float* __restrict__ Wih0, const float* __restrict__ Whh0, const float* __restrict__ b0,
    const float* __restrict__ Wih1, const float* __restrict__ Whh1, const float* __restrict__ b1,
    const float* __restrict__ Wc,   const float* __restrict__ bc,
    float* __restrict__ out)
{
    __shared__ __align__(16) float h1buf[2][NB][NHP];
    __shared__ __align__(16) float h2buf[2][NB][NHP];
    __shared__ __align__(16) float qbuf[NB][4][NHP];  // [batch][gate][unit]
    __shared__ float xbuf[4][NB][NI];                 // 4-slot x staging, t+2 ahead

    const int tid   = threadIdx.x;
    const int bbase = blockIdx.x * NB;

    // zero both h slots (pads included -> pads stay 0 forever; w pads are 0 too)
    for (int idx = tid; idx < 2 * NB * NHP; idx += BLK) {
        (&h1buf[0][0][0])[idx] = 0.0f;
        (&h2buf[0][0][0])[idx] = 0.0f;
    }
    // preload x(0), x(1)
    if (tid < 2 * NB * NI) {
        const int slot = tid / (NB * NI), r2 = tid % (NB * NI);
        const int b = r2 / NI, i = r2 % NI;
        xbuf[slot][b][i] = x[((size_t)(bbase + b) * TT + slot) * NI + i];
    }

    // roles in 160-thread (quad-aligned) groups:
    // 0 = L1 (full layer-1 cell), 1 = L2q (Whh1 partial), 2 = L2p (combine+cell),
    // 3 = x prefetch
    int role, l;
    if      (tid < 160) { role = 0; l = tid; }
    else if (tid < 320) { role = 1; l = tid - 160; }
    else if (tid < 480) { role = 2; l = tid - 320; }
    else                { role = 3; l = tid - 480; }

    // thread = one gate row (u,g), all NB batches; rows padded 152->160
    const int u   = (role <= 2) ? (l >> 2) : 0;   // 0..39, valid < 38
    const int g   = (role <= 2) ? (l & 3)  : 0;   // quads aligned (160 % 4 == 0)
    const bool act = (role <= 2) && (u < NH);
    const int uc  = (u < NH) ? u : 0;             // clamp for safe global loads
    const int grow = g * NH + uc;                 // gate-row in 4H-major layout

    // register-resident weights: exactly ONE row (~46 floats) -> no spill
    float w[NHP];                 // L1: Whh0 row; L2q: Whh1 row; L2p: Wih1 row
    float wx[NI] = {0,0,0,0,0,0}; // L1 only: Wih0 row
    float bias = 0.0f;
    float cst[NB] = {0.f, 0.f, 0.f, 0.f};

    if (role <= 2) {
        const float* rw = (role == 0) ? (Whh0 + (size_t)grow * NH)
                        : (role == 1) ? (Whh1 + (size_t)grow * NH)
                        :               (Wih1 + (size_t)grow * NH);
        #pragma unroll
        for (int k = 0; k < NH; ++k) w[k] = rw[k];
        w[38] = 0.f; w[39] = 0.f;
        if (role == 0) {
            const float* rx = Wih0 + (size_t)grow * NI;
            #pragma unroll
            for (int i = 0; i < NI; ++i) wx[i] = rx[i];
            bias = b0[grow];
        } else if (role == 2) {
            bias = b1[grow];
        }
    }

    // own-gate activation: gate 2 is tanh(a) = 2*sigmoid(2a) - 1
    const float k1 = (g == 2) ? 2.0f : 1.0f;
    const float k2 = (g == 2) ? 2.0f : 1.0f;
    const float k3 = (g == 2) ? -1.0f : 0.0f;

    __syncthreads();

    #pragma unroll 1
    for (int t = 0; t < TT; ++t) {
        const int cur = t & 1, prv = cur ^ 1, xs = t & 3;

        // ---------------- phase 1 ----------------
        if (role == 0) {
            // layer 1: a = b0 + Wih0 x(t) + Whh0 h1(t-1); pointwise via quad swizzle
            float acc[NB];
            #pragma unroll
            for (int b = 0; b < NB; ++b) {
                acc[b] = bias;
                #pragma unroll
                for (int i = 0; i < NI; ++i) acc[b] += wx[i] * xbuf[xs][b][i];
            }
            const float4* h4 = (const float4*)(&h1buf[prv][0][0]);
            #pragma unroll
            for (int c4 = 0; c4 < 10; ++c4) {
                #pragma unroll
                for (int b = 0; b < NB; ++b) {   // independent FMA chains
                    const float4 hv = h4[b * 10 + c4];   // wave-broadcast read
                    acc[b] += w[4*c4+0] * hv.x; acc[b] += w[4*c4+1] * hv.y;
                    acc[b] += w[4*c4+2] * hv.z; acc[b] += w[4*c4+3] * hv.w;
                }
            }
            #pragma unroll
            for (int b = 0; b < NB; ++b) {
                const float v  = fsig(acc[b] * k1) * k2 + k3;
                const float gi = QBCAST(v, QB0);
                const float gf = QBCAST(v, QB1);
                const float gg = QBCAST(v, QB2);
                const float go = QBCAST(v, QB3);
                const float c  = gf * cst[b] + gi * gg;
                cst[b] = c;
                const float h = go * (2.0f * fsig(2.0f * c) - 1.0f);
                if (act && g == 0) h1buf[cur][b][u] = h;
            }
        } else if (role == 1) {
            // layer-2 recurrent partial: q = Whh1 h2(t-1)  (independent of h1(t))
            float acc[NB] = {0.f, 0.f, 0.f, 0.f};
            const float4* h4 = (const float4*)(&h2buf[prv][0][0]);
            #pragma unroll
            for (int c4 = 0; c4 < 10; ++c4) {
                #pragma unroll
                for (int b = 0; b < NB; ++b) {
                    const float4 hv = h4[b * 10 + c4];
                    acc[b] += w[4*c4+0] * hv.x; acc[b] += w[4*c4+1] * hv.y;
                    acc[b] += w[4*c4+2] * hv.z; acc[b] += w[4*c4+3] * hv.w;
                }
            }
            if (act) {
                #pragma unroll
                for (int b = 0; b < NB; ++b) qbuf[b][g][u] = acc[b];
            }
        } else if (role == 3) {
            // x prefetch, 2 steps ahead (HBM latency hidden across 2 steps)
            if (l < NB * NI && t + 2 < TT) {
                const int b = l / NI, i = l % NI;
                xbuf[(t + 2) & 3][b][i] = x[((size_t)(bbase + b) * TT + (t + 2)) * NI + i];
            }
        }
        __syncthreads();

        // ---------------- phase 2 ----------------
        if (role == 2) {
            // layer 2: a = b1 + q + Wih1 h1(t); pointwise via quad swizzle
            float acc[NB];
            #pragma unroll
            for (int b = 0; b < NB; ++b) acc[b] = bias + qbuf[b][g][u];
            const float4* h4 = (const float4*)(&h1buf[cur][0][0]);
            #pragma unroll
            for (int c4 = 0; c4 < 10; ++c4) {
                #pragma unroll
                for (int b = 0; b < NB; ++b) {
                    const float4 hv = h4[b * 10 + c4];
                    acc[b] += w[4*c4+0] * hv.x; acc[b] += w[4*c4+1] * hv.y;
                    acc[b] += w[4*c4+2] * hv.z; acc[b] += w[4*c4+3] * hv.w;
                }
            }
            #pragma unroll
            for (int b = 0; b < NB; ++b) {
                const float v  = fsig(acc[b] * k1) * k2 + k3;
                const float gi = QBCAST(v, QB0);
                const float gf = QBCAST(v, QB1);
                const float gg = QBCAST(v, QB2);
                const float go = QBCAST(v, QB3);
                const float c  = gf * cst[b] + gi * gg;
                cst[b] = c;
                const float h = go * (2.0f * fsig(2.0f * c) - 1.0f);
                if (act && g == 0) h2buf[cur][b][u] = h;
            }
        }
        __syncthreads();
    }

    // epilogue: out = h2(T-1) @ Wc.T + bc ; TT-1 odd -> slot 1
    if (tid < NB * NCLS) {
        const int b = tid / NCLS, c = tid % NCLS;
        float acc = bc[c];
        #pragma unroll
        for (int k = 0; k < NH; ++k) acc += Wc[c * NH + k] * h2buf[1][b][k];
        out[(size_t)(bbase + b) * NCLS + c] = acc;
    }
}

extern "C" void kernel_launch(void* const* d_in, const int* in_sizes, int n_in,
                              void* d_out, int out_size, void* d_ws, size_t ws_size,
                              hipStream_t stream) {
    const float* x    = (const float*)d_in[0];
    const float* Wih0 = (const float*)d_in[1];
    const float* Whh0 = (const float*)d_in[2];
    const float* b0   = (const float*)d_in[3];
    const float* Wih1 = (const float*)d_in[4];
    const float* Whh1 = (const float*)d_in[5];
    const float* b1   = (const float*)d_in[6];
    const float* Wc   = (const float*)d_in[7];
    const float* bc   = (const float*)d_in[8];
    float* out = (float*)d_out;

    hipLaunchKernelGGL(lstm2_kernel, dim3(GRID), dim3(BLK), 0, stream,
                       x, Wih0, Whh0, b0, Wih1, Whh1, b1, Wc, bc, out);
}